// Round 9
// baseline (23256.947 us; speedup 1.0000x reference)
//
#include <hip/hip_runtime.h>

#define B_ 64
#define T_ 4096
#define IN_ 128
#define H_ 256
#define TPB 256

using u64 = unsigned long long;
using u32 = unsigned int;
typedef _Float16 h2_t __attribute__((ext_vector_type(2)));

// global h buffer: [2][B][4 chunks][32 slots] of {ver32 | f16x2}
static constexpr size_t PSTR    = (size_t)B_ * 4 * 32;        // parity stride (u64)
static constexpr size_t GHB_U64 = 2 * PSTR;                   // 16384 u64 = 128 KiB

__device__ __forceinline__ float fast_rcp(float x) { return __builtin_amdgcn_rcpf(x); }
__device__ __forceinline__ float fast_sigmoid(float x) {
    return fast_rcp(1.0f + __expf(-x));
}
__device__ __forceinline__ float fast_tanh(float x) {
    float ax = fabsf(x);
    float e  = __expf(-2.0f * ax);
    float t  = (1.0f - e) * fast_rcp(1.0f + e);
    return copysignf(t, x);
}
__device__ __forceinline__ u64 ld_agent(const u64* p) {
    return __hip_atomic_load(p, __ATOMIC_RELAXED, __HIP_MEMORY_SCOPE_AGENT);
}
__device__ __forceinline__ void st_agent(u64* p, u64 v) {
    __hip_atomic_store(p, v, __ATOMIC_RELAXED, __HIP_MEMORY_SCOPE_AGENT);
}
__device__ __forceinline__ u64 ld_lds(const u64* p) {
    return __hip_atomic_load(p, __ATOMIC_RELAXED, __HIP_MEMORY_SCOPE_WORKGROUP);
}
__device__ __forceinline__ void st_lds(u64* p, u64 v) {
    __hip_atomic_store(p, v, __ATOMIC_RELAXED, __HIP_MEMORY_SCOPE_WORKGROUP);
}
// barrier draining LDS only — global loads/stores stay in flight
__device__ __forceinline__ void barrier_lgkm() {
    asm volatile("s_waitcnt lgkmcnt(0)" ::: "memory");
    __builtin_amdgcn_s_barrier();
}
__device__ __forceinline__ u32 pk16(float a, float b) {
    return __builtin_bit_cast(u32, __builtin_amdgcn_cvt_pkrtz(a, b));
}

__global__ __launch_bounds__(TPB, 1) void lstm_persist(
    const float* __restrict__ x,      // [B,T,IN]
    const float* __restrict__ W_ih,   // [1024,128]
    const float* __restrict__ W_hh,   // [1024,256]
    const float* __restrict__ b_ih,
    const float* __restrict__ b_hh,
    const float* __restrict__ fc_w,   // [128,256]
    const float* __restrict__ fc_b,   // [128]
    float* __restrict__ out,          // [B,128]
    u64* ghb)                         // [2][B][4][32]
{
    const int blk  = blockIdx.x;      // 256 blocks: (b, s)
    const int b    = blk >> 2;
    const int s    = blk & 3;         // h-slice this block PRODUCES
    const int tid  = threadIdx.x;
    const int lane = tid & 63;
    const int w    = tid >> 6;        // 4 waves; wave w owns K-interleave slice w
    const int wS   = __builtin_amdgcn_readfirstlane(w);
    const bool is_upd = (w == s);

    // the three remote chunks (all != s, ascending)
    const int r0 = (s == 0) ? 1 : 0;
    const int r1 = (s <= 1) ? 2 : 1;
    const int r2 = (s <= 2) ? 3 : 2;

    // --- persistent f16-packed weights ---
    // hh: rows g (grow = g*256+s*64+lane), pair idx c*8+pp <-> K = c*64 + w*16 + 2pp
    u32 whh[4][32];
    #pragma unroll
    for (int g = 0; g < 4; ++g) {
        const float* rowp = W_hh + (size_t)(g * 256 + s * 64 + lane) * H_;
        #pragma unroll
        for (int c = 0; c < 4; ++c)
            #pragma unroll
            for (int pp = 0; pp < 8; ++pp) {
                const float2 v = *(const float2*)(rowp + c * 64 + w * 16 + 2 * pp);
                whh[g][c * 8 + pp] = pk16(v.x, v.y);
            }
    }
    // ih: pair idx pp <-> K = w*32 + 2pp
    u32 wih[4][16];
    #pragma unroll
    for (int g = 0; g < 4; ++g) {
        const float* rowp = W_ih + (size_t)(g * 256 + s * 64 + lane) * IN_;
        #pragma unroll
        for (int pp = 0; pp < 16; ++pp) {
            const float2 v = *(const float2*)(rowp + w * 32 + 2 * pp);
            wih[g][pp] = pk16(v.x, v.y);
        }
    }
    float bias_[4] = {0.f, 0.f, 0.f, 0.f};
    if (is_upd) {
        #pragma unroll
        for (int g = 0; g < 4; ++g)
            bias_[g] = b_ih[g * 256 + s * 64 + lane] + b_hh[g * 256 + s * 64 + lane];
    }

    __shared__ float part[2][4][4][64];   // [parity][wave][gate][lane]
    __shared__ u64 hlds[2][32];           // local chunk handoff {ver | f16x2}
    if (tid < 32) { hlds[0][tid] = 0; hlds[1][tid] = 0; }
    __syncthreads();

    float c_own = 0.0f;                   // producer wave: c for h-index (s*64+lane)

    const float* xb = x + (size_t)b * T_ * IN_;
    float2 vx0, vx1;
    if (lane < 16) {
        vx0 = *(const float2*)(xb + w * 32 + 2 * lane);
        vx1 = *(const float2*)(xb + IN_ + w * 32 + 2 * lane);
    }

    // poll/store addresses (parity 0); ghb idx = ((p*B+b)*4 + c)*32 + slot
    const u64* A0 = ghb + ((size_t)b * 4 + (lane < 32 ? r0 : r1)) * 32 + (lane & 31);
    const u64* B0 = ghb + ((size_t)b * 4 + r2) * 32 + (lane & 31);
    u64* const S0 = ghb + ((size_t)b * 4 + s) * 32 + (lane & 31);

    for (int t = 0; t < T_; ++t) {
        const int p  = t & 1;
        const int pn = p ^ 1;
        const u32 tv = (u32)t;
        const u64* pA = A0 + (size_t)p * PSTR;
        const u64* pB = B0 + (size_t)p * PSTR;

        // early issue: remote polls + local LDS probe (latency hides under ih)
        u64 vA = ld_agent(pA);
        u64 vB = ld_agent(pB);
        u64 vL = ld_lds(&hlds[p][lane & 31]);

        // ih contribution (x pairs live in lanes 0..15)
        const u32 xpk = pk16(vx0.x, vx0.y);
        float a0 = bias_[0], a1 = bias_[1], a2 = bias_[2], a3 = bias_[3];
        #pragma unroll
        for (int pp = 0; pp < 16; ++pp) {
            const h2_t xp = __builtin_bit_cast(h2_t, __builtin_amdgcn_readlane(xpk, pp));
            a0 = __builtin_amdgcn_fdot2(__builtin_bit_cast(h2_t, wih[0][pp]), xp, a0, false);
            a1 = __builtin_amdgcn_fdot2(__builtin_bit_cast(h2_t, wih[1][pp]), xp, a1, false);
            a2 = __builtin_amdgcn_fdot2(__builtin_bit_cast(h2_t, wih[2][pp]), xp, a2, false);
            a3 = __builtin_amdgcn_fdot2(__builtin_bit_cast(h2_t, wih[3][pp]), xp, a3, false);
        }

        // remote spin (2 in-flight loads cover all 3 chunks)
        while ((u32)(vA >> 32) < tv || (u32)(vB >> 32) < tv) {
            vA = ld_agent(pA);
            vB = ld_agent(pB);
        }
        // local chunk spin (LDS, ~ready by now)
        while ((u32)(vL >> 32) < tv) vL = ld_lds(&hlds[p][lane & 31]);

        // x prefetch (distance 2) AFTER all spins — never on the spin's waitcnt
        vx0 = vx1;
        {
            const int tf = (t + 2 < T_) ? (t + 2) : (T_ - 1);
            if (lane < 16) vx1 = *(const float2*)(xb + (size_t)tf * IN_ + w * 32 + 2 * lane);
        }

        // hh: 4 chunks x 8 pairs, 1 readlane + 4 dot2 per pair
        const u32 loA = (u32)vA, loB = (u32)vB, loL = (u32)vL;
        auto mac8 = [&](int cbase, u32 reg, int lofs) {
            #pragma unroll
            for (int pp = 0; pp < 8; ++pp) {
                const h2_t hp = __builtin_bit_cast(h2_t,
                    __builtin_amdgcn_readlane(reg, lofs + wS * 8 + pp));
                a0 = __builtin_amdgcn_fdot2(__builtin_bit_cast(h2_t, whh[0][cbase + pp]), hp, a0, false);
                a1 = __builtin_amdgcn_fdot2(__builtin_bit_cast(h2_t, whh[1][cbase + pp]), hp, a1, false);
                a2 = __builtin_amdgcn_fdot2(__builtin_bit_cast(h2_t, whh[2][cbase + pp]), hp, a2, false);
                a3 = __builtin_amdgcn_fdot2(__builtin_bit_cast(h2_t, whh[3][cbase + pp]), hp, a3, false);
            }
        };
        mac8(s  * 8, loL, 0);    // local chunk
        mac8(r0 * 8, loA, 0);    // remote chunks
        mac8(r1 * 8, loA, 32);
        mac8(r2 * 8, loB, 0);

        part[p][w][0][lane] = a0;
        part[p][w][1][lane] = a1;
        part[p][w][2][lane] = a2;
        part[p][w][3][lane] = a3;

        barrier_lgkm();          // LDS-only drain; global ops ride across

        if (is_upd) {
            const float gi = part[p][0][0][lane] + part[p][1][0][lane]
                           + part[p][2][0][lane] + part[p][3][0][lane];
            const float gf = part[p][0][1][lane] + part[p][1][1][lane]
                           + part[p][2][1][lane] + part[p][3][1][lane];
            const float gg = part[p][0][2][lane] + part[p][1][2][lane]
                           + part[p][2][2][lane] + part[p][3][2][lane];
            const float go = part[p][0][3][lane] + part[p][1][3][lane]
                           + part[p][2][3][lane] + part[p][3][3][lane];
            const float i_ = fast_sigmoid(gi);
            const float f_ = fast_sigmoid(gf);
            const float g_ = fast_tanh(gg);
            const float o_ = fast_sigmoid(go);
            c_own = fmaf(f_, c_own, i_ * g_);
            const float h_ = o_ * fast_tanh(c_own);
            // pack pairs: slot j (lanes 0..31) = {h[s*64+2j], h[s*64+2j+1]}
            const float he = __shfl(h_, 2 * (lane & 31));
            const float ho = __shfl(h_, 2 * (lane & 31) + 1);
            const u64 msg = ((u64)(u32)(t + 1) << 32) | (u64)pk16(he, ho);
            if (lane < 32) {
                st_agent(S0 + (size_t)pn * PSTR, msg);   // remote path first (critical)
                st_lds(&hlds[pn][lane], msg);            // local handoff
            }
        }
        // part[] and hlds[] are parity-double-buffered; one barrier per step
    }

    // ---- final FC: out[b, 32s .. 32s+32) ---- (T_ even -> parity 0)
    const u64* hT = ghb + (size_t)b * 4 * 32;
    const int c = s * 32 + (tid >> 3);
    const int q = tid & 7;
    float acc = 0.0f;
    #pragma unroll
    for (int e = 0; e < 32; ++e) {
        const int k = q * 32 + e;
        const u64* ps = hT + (k >> 6) * 32 + ((k >> 1) & 31);
        u64 v;
        do { v = ld_agent(ps); } while ((u32)(v >> 32) < (u32)T_);
        const h2_t h2 = __builtin_bit_cast(h2_t, (u32)v);
        const float hv = (float)((k & 1) ? h2.y : h2.x);
        acc = fmaf(fc_w[(size_t)c * H_ + k], hv, acc);
    }
    acc += __shfl_xor(acc, 1);
    acc += __shfl_xor(acc, 2);
    acc += __shfl_xor(acc, 4);
    if (q == 0) out[(size_t)b * 128 + c] = acc + fc_b[c];
}

extern "C" void kernel_launch(void* const* d_in, const int* in_sizes, int n_in,
                              void* d_out, int out_size, void* d_ws, size_t ws_size,
                              hipStream_t stream) {
    const float* x    = (const float*)d_in[0];
    const float* W_ih = (const float*)d_in[1];
    const float* W_hh = (const float*)d_in[2];
    const float* b_ih = (const float*)d_in[3];
    const float* b_hh = (const float*)d_in[4];
    const float* fc_w = (const float*)d_in[5];
    const float* fc_b = (const float*)d_in[6];
    float* out = (float*)d_out;

    u64* ghb = (u64*)d_ws;
    // {ver=0, h=0} everywhere == correct initial state
    hipMemsetAsync(d_ws, 0, GHB_U64 * sizeof(u64), stream);

    lstm_persist<<<B_ * 4, TPB, 0, stream>>>(x, W_ih, W_hh, b_ih, b_hh, fc_w, fc_b,
                                             out, ghb);
}

// Round 10
// 7195.164 us; speedup vs baseline: 3.2323x; 3.2323x over previous
//
#include <hip/hip_runtime.h>

#define B_ 64
#define T_ 4096
#define IN_ 128
#define H_ 256
#define TPB 256

using u64 = unsigned long long;
using u32 = unsigned int;
typedef _Float16 h2_t __attribute__((ext_vector_type(2)));

// global h buffer: [2][B][4 chunks][32 slots] of {ver32 | f16x2}
static constexpr size_t PSTR    = (size_t)B_ * 4 * 32;        // parity stride (u64)
static constexpr size_t GHB_U64 = 2 * PSTR;                   // 16384 u64 = 128 KiB

__device__ __forceinline__ float fast_rcp(float x) { return __builtin_amdgcn_rcpf(x); }
__device__ __forceinline__ float fast_sigmoid(float x) {
    return fast_rcp(1.0f + __expf(-x));
}
__device__ __forceinline__ float fast_tanh(float x) {
    float ax = fabsf(x);
    float e  = __expf(-2.0f * ax);
    float t  = (1.0f - e) * fast_rcp(1.0f + e);
    return copysignf(t, x);
}
__device__ __forceinline__ u64 ld_agent(const u64* p) {
    return __hip_atomic_load(p, __ATOMIC_RELAXED, __HIP_MEMORY_SCOPE_AGENT);
}
__device__ __forceinline__ void st_agent(u64* p, u64 v) {
    __hip_atomic_store(p, v, __ATOMIC_RELAXED, __HIP_MEMORY_SCOPE_AGENT);
}
__device__ __forceinline__ u64 ld_lds(const u64* p) {
    return __hip_atomic_load(p, __ATOMIC_RELAXED, __HIP_MEMORY_SCOPE_WORKGROUP);
}
__device__ __forceinline__ void st_lds(u64* p, u64 v) {
    __hip_atomic_store(p, v, __ATOMIC_RELAXED, __HIP_MEMORY_SCOPE_WORKGROUP);
}
// barrier draining LDS only — global loads/stores stay in flight
__device__ __forceinline__ void barrier_lgkm() {
    asm volatile("s_waitcnt lgkmcnt(0)" ::: "memory");
    __builtin_amdgcn_s_barrier();
}
__device__ __forceinline__ u32 pk16(float a, float b) {
    return __builtin_bit_cast(u32, __builtin_amdgcn_cvt_pkrtz(a, b));
}

__global__ __launch_bounds__(TPB, 1) void lstm_persist(
    const float* __restrict__ x,      // [B,T,IN]
    const float* __restrict__ W_ih,   // [1024,128]
    const float* __restrict__ W_hh,   // [1024,256]
    const float* __restrict__ b_ih,
    const float* __restrict__ b_hh,
    const float* __restrict__ fc_w,   // [128,256]
    const float* __restrict__ fc_b,   // [128]
    float* __restrict__ out,          // [B,128]
    u64* ghb)                         // [2][B][4][32]
{
    const int blk  = blockIdx.x;      // 256 blocks: (b, s)
    const int b    = blk >> 2;
    const int s    = blk & 3;         // h-slice this block PRODUCES
    const int tid  = threadIdx.x;
    const int lane = tid & 63;
    const int w    = tid >> 6;        // 4 waves; wave w owns K-interleave slice w
    const int wS   = __builtin_amdgcn_readfirstlane(w);
    const bool is_upd = (w == s);

    // the three remote chunks (all != s, ascending)
    const int r0 = (s == 0) ? 1 : 0;
    const int r1 = (s <= 1) ? 2 : 1;
    const int r2 = (s <= 2) ? 3 : 2;

    // --- persistent f16-packed weights, stored in CONSUMPTION order ---
    // register pair index q*8+pp  <->  K-column chunk(q)*64 + w*16 + 2pp
    // q: 0=local(s), 1=r0, 2=r1, 3=r2  — q is COMPILE-TIME (rule #20 fix)
    u32 whh[4][32];
    #pragma unroll
    for (int g = 0; g < 4; ++g) {
        const float* rowp = W_hh + (size_t)(g * 256 + s * 64 + lane) * H_;
        #pragma unroll
        for (int q = 0; q < 4; ++q) {
            const int cc = (q == 0) ? s : ((q == 1) ? r0 : ((q == 2) ? r1 : r2));
            #pragma unroll
            for (int pp = 0; pp < 8; ++pp) {
                const float2 v = *(const float2*)(rowp + cc * 64 + w * 16 + 2 * pp);
                whh[g][q * 8 + pp] = pk16(v.x, v.y);
            }
        }
    }
    // ih: pair idx pp <-> K = w*32 + 2pp
    u32 wih[4][16];
    #pragma unroll
    for (int g = 0; g < 4; ++g) {
        const float* rowp = W_ih + (size_t)(g * 256 + s * 64 + lane) * IN_;
        #pragma unroll
        for (int pp = 0; pp < 16; ++pp) {
            const float2 v = *(const float2*)(rowp + w * 32 + 2 * pp);
            wih[g][pp] = pk16(v.x, v.y);
        }
    }
    float bias_[4] = {0.f, 0.f, 0.f, 0.f};
    if (is_upd) {
        #pragma unroll
        for (int g = 0; g < 4; ++g)
            bias_[g] = b_ih[g * 256 + s * 64 + lane] + b_hh[g * 256 + s * 64 + lane];
    }

    __shared__ float part[2][4][4][64];   // [parity][wave][gate][lane]
    __shared__ u64 hlds[2][32];           // local chunk handoff {ver | f16x2}
    if (tid < 32) { hlds[0][tid] = 0; hlds[1][tid] = 0; }
    __syncthreads();

    float c_own = 0.0f;                   // producer wave: c for h-index (s*64+lane)

    const float* xb = x + (size_t)b * T_ * IN_;
    float2 vx0, vx1;
    if (lane < 16) {
        vx0 = *(const float2*)(xb + w * 32 + 2 * lane);
        vx1 = *(const float2*)(xb + IN_ + w * 32 + 2 * lane);
    }

    // poll/store addresses (parity 0); ghb idx = ((p*B+b)*4 + c)*32 + slot
    const u64* A0 = ghb + ((size_t)b * 4 + (lane < 32 ? r0 : r1)) * 32 + (lane & 31);
    const u64* B0 = ghb + ((size_t)b * 4 + r2) * 32 + (lane & 31);
    u64* const S0 = ghb + ((size_t)b * 4 + s) * 32 + (lane & 31);

    for (int t = 0; t < T_; ++t) {
        const int p  = t & 1;
        const int pn = p ^ 1;
        const u32 tv = (u32)t;
        const u64* pA = A0 + (size_t)p * PSTR;
        const u64* pB = B0 + (size_t)p * PSTR;

        // early issue: remote polls + local LDS probe (latency hides under ih)
        u64 vA = ld_agent(pA);
        u64 vB = ld_agent(pB);
        u64 vL = ld_lds(&hlds[p][lane & 31]);

        // ih contribution (x pairs live in lanes 0..15)
        const u32 xpk = pk16(vx0.x, vx0.y);
        float a0 = bias_[0], a1 = bias_[1], a2 = bias_[2], a3 = bias_[3];
        #pragma unroll
        for (int pp = 0; pp < 16; ++pp) {
            const h2_t xp = __builtin_bit_cast(h2_t, __builtin_amdgcn_readlane(xpk, pp));
            a0 = __builtin_amdgcn_fdot2(__builtin_bit_cast(h2_t, wih[0][pp]), xp, a0, false);
            a1 = __builtin_amdgcn_fdot2(__builtin_bit_cast(h2_t, wih[1][pp]), xp, a1, false);
            a2 = __builtin_amdgcn_fdot2(__builtin_bit_cast(h2_t, wih[2][pp]), xp, a2, false);
            a3 = __builtin_amdgcn_fdot2(__builtin_bit_cast(h2_t, wih[3][pp]), xp, a3, false);
        }

        // remote spin (2 in-flight loads cover all 3 chunks)
        while ((u32)(vA >> 32) < tv || (u32)(vB >> 32) < tv) {
            vA = ld_agent(pA);
            vB = ld_agent(pB);
        }
        // local chunk spin (LDS, ~ready by now)
        while ((u32)(vL >> 32) < tv) vL = ld_lds(&hlds[p][lane & 31]);

        // x prefetch (distance 2) AFTER all spins — never on the spin's waitcnt
        vx0 = vx1;
        {
            const int tf = (t + 2 < T_) ? (t + 2) : (T_ - 1);
            if (lane < 16) vx1 = *(const float2*)(xb + (size_t)tf * IN_ + w * 32 + 2 * lane);
        }

        // hh: 4 chunks x 8 pairs, 1 readlane + 4 dot2 per pair
        // register base is COMPILE-TIME; only the readlane source reg differs
        const u32 loA = (u32)vA, loB = (u32)vB, loL = (u32)vL;
        auto mac8 = [&](const int cbase, const u32 reg, const int lofs) {
            #pragma unroll
            for (int pp = 0; pp < 8; ++pp) {
                const h2_t hp = __builtin_bit_cast(h2_t,
                    __builtin_amdgcn_readlane(reg, lofs + wS * 8 + pp));
                a0 = __builtin_amdgcn_fdot2(__builtin_bit_cast(h2_t, whh[0][cbase + pp]), hp, a0, false);
                a1 = __builtin_amdgcn_fdot2(__builtin_bit_cast(h2_t, whh[1][cbase + pp]), hp, a1, false);
                a2 = __builtin_amdgcn_fdot2(__builtin_bit_cast(h2_t, whh[2][cbase + pp]), hp, a2, false);
                a3 = __builtin_amdgcn_fdot2(__builtin_bit_cast(h2_t, whh[3][cbase + pp]), hp, a3, false);
            }
        };
        mac8(0,  loL, 0);    // local chunk   (regs  0..7)
        mac8(8,  loA, 0);    // r0            (regs  8..15)
        mac8(16, loA, 32);   // r1            (regs 16..23)
        mac8(24, loB, 0);    // r2            (regs 24..31)

        part[p][w][0][lane] = a0;
        part[p][w][1][lane] = a1;
        part[p][w][2][lane] = a2;
        part[p][w][3][lane] = a3;

        barrier_lgkm();          // LDS-only drain; global ops ride across

        if (is_upd) {
            const float gi = part[p][0][0][lane] + part[p][1][0][lane]
                           + part[p][2][0][lane] + part[p][3][0][lane];
            const float gf = part[p][0][1][lane] + part[p][1][1][lane]
                           + part[p][2][1][lane] + part[p][3][1][lane];
            const float gg = part[p][0][2][lane] + part[p][1][2][lane]
                           + part[p][2][2][lane] + part[p][3][2][lane];
            const float go = part[p][0][3][lane] + part[p][1][3][lane]
                           + part[p][2][3][lane] + part[p][3][3][lane];
            const float i_ = fast_sigmoid(gi);
            const float f_ = fast_sigmoid(gf);
            const float g_ = fast_tanh(gg);
            const float o_ = fast_sigmoid(go);
            c_own = fmaf(f_, c_own, i_ * g_);
            const float h_ = o_ * fast_tanh(c_own);
            // pack pairs: slot j (lanes 0..31) = {h[s*64+2j], h[s*64+2j+1]}
            const float he = __shfl(h_, 2 * (lane & 31));
            const float ho = __shfl(h_, 2 * (lane & 31) + 1);
            const u64 msg = ((u64)(u32)(t + 1) << 32) | (u64)pk16(he, ho);
            if (lane < 32) {
                st_agent(S0 + (size_t)pn * PSTR, msg);   // remote path first (critical)
                st_lds(&hlds[pn][lane], msg);            // local handoff
            }
        }
        // part[] and hlds[] are parity-double-buffered; one barrier per step
    }

    // ---- final FC: out[b, 32s .. 32s+32) ---- (T_ even -> parity 0)
    const u64* hT = ghb + (size_t)b * 4 * 32;
    const int c = s * 32 + (tid >> 3);
    const int q = tid & 7;
    float acc = 0.0f;
    #pragma unroll
    for (int e = 0; e < 32; ++e) {
        const int k = q * 32 + e;
        const u64* ps = hT + (k >> 6) * 32 + ((k >> 1) & 31);
        u64 v;
        do { v = ld_agent(ps); } while ((u32)(v >> 32) < (u32)T_);
        const h2_t h2 = __builtin_bit_cast(h2_t, (u32)v);
        const float hv = (float)((k & 1) ? h2.y : h2.x);
        acc = fmaf(fc_w[(size_t)c * H_ + k], hv, acc);
    }
    acc += __shfl_xor(acc, 1);
    acc += __shfl_xor(acc, 2);
    acc += __shfl_xor(acc, 4);
    if (q == 0) out[(size_t)b * 128 + c] = acc + fc_b[c];
}

extern "C" void kernel_launch(void* const* d_in, const int* in_sizes, int n_in,
                              void* d_out, int out_size, void* d_ws, size_t ws_size,
                              hipStream_t stream) {
    const float* x    = (const float*)d_in[0];
    const float* W_ih = (const float*)d_in[1];
    const float* W_hh = (const float*)d_in[2];
    const float* b_ih = (const float*)d_in[3];
    const float* b_hh = (const float*)d_in[4];
    const float* fc_w = (const float*)d_in[5];
    const float* fc_b = (const float*)d_in[6];
    float* out = (float*)d_out;

    u64* ghb = (u64*)d_ws;
    // {ver=0, h=0} everywhere == correct initial state
    hipMemsetAsync(d_ws, 0, GHB_U64 * sizeof(u64), stream);

    lstm_persist<<<B_ * 4, TPB, 0, stream>>>(x, W_ih, W_hh, b_ih, b_hh, fc_w, fc_b,
                                             out, ghb);
}